// Round 1
// baseline (64467.761 us; speedup 1.0000x reference)
//
#include <hip/hip_runtime.h>
#include <cstdint>
#include <cstddef>

// ---------------------------------------------------------------------------
// GRU, persistent single-kernel design for MI355X (gfx950).
//   T=512 steps, B=64, I=1024, Hd=2048. f32 I/O, bf16 MFMA internally.
//
//   grid = 128 blocks x 512 threads (8 waves). Per step two phases separated
//   by device-scope grid barriers:
//     phase A: blocks 0..63  -> Z cols [32b,32b+32)   (K = I(X) + H(H))
//              blocks 64..127-> R cols, store RH=R*H (bf16)
//     phase B: blocks 0..63  -> H~ cols, H_new (Z,H held in registers!)
//              blocks 64..95 -> Y_{t-1} = H_t @ W_hq (t>0)
//              blocks 96..127-> convert X_{t+1} f32->bf16
//   Weights converted f32->bf16 + transposed (N-major, K-contiguous) once per
//   launch so B-fragments are single 16B lane loads straight from L2.
// ---------------------------------------------------------------------------

#define T_ 512
#define B_ 64
#define I_ 1024
#define H_ 2048
#define NB 128
#define NTHREADS 512
#define GSTRIDE (NB * NTHREADS)

typedef __attribute__((ext_vector_type(8))) __bf16 bf16x8;
typedef __attribute__((ext_vector_type(4))) float f32x4;

// ---- workspace layout (bytes) ----
static constexpr size_t OFF_BAR  = 0;
static constexpr size_t OFF_WXZT = 256;
static constexpr size_t SZ_WXT   = (size_t)H_ * I_ * 2;   // WxT: N=2048 rows, K=1024
static constexpr size_t SZ_WHT   = (size_t)H_ * H_ * 2;   // WhT: N=2048 rows, K=2048
static constexpr size_t OFF_WXRT = OFF_WXZT + SZ_WXT;
static constexpr size_t OFF_WXHT = OFF_WXRT + SZ_WXT;
static constexpr size_t OFF_WHZT = OFF_WXHT + SZ_WXT;
static constexpr size_t OFF_WHRT = OFF_WHZT + SZ_WHT;
static constexpr size_t OFF_WHHT = OFF_WHRT + SZ_WHT;
static constexpr size_t OFF_WHQT = OFF_WHHT + SZ_WHT;     // WhqT: N=1024 rows, K=2048 (4MiB)
static constexpr size_t OFF_XBF  = OFF_WHQT + SZ_WXT;
static constexpr size_t OFF_HBF  = OFF_XBF + (size_t)2 * B_ * I_ * 2;
static constexpr size_t OFF_RHBF = OFF_HBF + (size_t)2 * B_ * H_ * 2;
static constexpr size_t WS_NEEDED = OFF_RHBF + (size_t)B_ * H_ * 2;

__device__ __forceinline__ float fsigmoid(float x) { return 1.0f / (1.0f + __expf(-x)); }
__device__ __forceinline__ float ftanh(float x)    { return 2.0f / (1.0f + __expf(-2.0f * x)) - 1.0f; }

// device-scope grid barrier (sense via monotonically increasing counter).
// All NB blocks are resident by construction (128 blocks, <=34KB LDS, 512 thr).
__device__ __forceinline__ void grid_sync(unsigned* bar, unsigned& target) {
    __threadfence();          // release: drain my stores device-wide
    __syncthreads();          // everyone in block done + fenced
    target += (unsigned)NB;
    if (threadIdx.x == 0) {
        __hip_atomic_fetch_add(bar, 1u, __ATOMIC_RELEASE, __HIP_MEMORY_SCOPE_AGENT);
        while (__hip_atomic_load(bar, __ATOMIC_ACQUIRE, __HIP_MEMORY_SCOPE_AGENT) < target) {
            __builtin_amdgcn_s_sleep(4);
        }
    }
    __syncthreads();
    __threadfence();          // acquire: invalidate stale cache before reads
}

// f32 (K x N row-major) -> bf16 transposed (N x K row-major)
__device__ __forceinline__ void transpose_cvt(const float* __restrict__ src,
                                              __bf16* __restrict__ dst,
                                              int K, int lgN) {
    const int N = 1 << lgN;
    const int total = K << lgN;
    for (int idx = (int)(blockIdx.x * blockDim.x + threadIdx.x); idx < total; idx += GSTRIDE) {
        int k = idx >> lgN;
        int n = idx & (N - 1);
        dst[(size_t)n * K + k] = (__bf16)src[idx];
    }
}

// Block GEMM: out tile = [64 rows x 32 cols], two K-segments (X-part, H-part).
// A row-major bf16 (row stride rs), Bt = weight^T (N-major, row len kr).
// 8 waves split K; cross-wave reduce through LDS. Every thread returns 4 sums
// for elements e = tid + i*512, e -> (row = e>>5, col = colbase + (e&31)).
__device__ void gemm_block(const __bf16* __restrict__ A0, int rs0, int ks0,
                           const __bf16* __restrict__ B0t, int kr0,
                           const __bf16* __restrict__ A1, int rs1, int ks1,
                           const __bf16* __restrict__ B1t, int kr1,
                           int colbase, float* __restrict__ red, float out4[4]) {
    const int tid  = (int)threadIdx.x;
    const int lane = tid & 63;
    const int w    = tid >> 6;
    const int l15  = lane & 15;
    const int q8   = (lane >> 4) << 3;   // k offset of this quad
    const int q4   = (lane >> 4) << 2;   // row offset (C/D layout)

    f32x4 acc[4][2];
#pragma unroll
    for (int m = 0; m < 4; ++m) {
        acc[m][0] = f32x4{0.f, 0.f, 0.f, 0.f};
        acc[m][1] = f32x4{0.f, 0.f, 0.f, 0.f};
    }

    auto do_seg = [&](const __bf16* __restrict__ A, int rs,
                      const __bf16* __restrict__ Bt, int kr, int kb) {
        bf16x8 b0 = *(const bf16x8*)(Bt + (size_t)(colbase + l15) * kr + kb);
        bf16x8 b1 = *(const bf16x8*)(Bt + (size_t)(colbase + 16 + l15) * kr + kb);
#pragma unroll
        for (int m = 0; m < 4; ++m) {
            bf16x8 av = *(const bf16x8*)(A + (size_t)((m << 4) + l15) * rs + kb);
            acc[m][0] = __builtin_amdgcn_mfma_f32_16x16x32_bf16(av, b0, acc[m][0], 0, 0, 0);
            acc[m][1] = __builtin_amdgcn_mfma_f32_16x16x32_bf16(av, b1, acc[m][1], 0, 0, 0);
        }
    };

    int s = w;
    for (; s < ks0; s += 8)        do_seg(A0, rs0, B0t, kr0, (s << 5) + q8);
    for (; s < ks0 + ks1; s += 8)  do_seg(A1, rs1, B1t, kr1, ((s - ks0) << 5) + q8);

    // cross-wave reduction: waves 4..7 dump, waves 0..3 add in, then gather.
    if (w >= 4) {
        float* rw = red + (size_t)(w - 4) * (64 * 33);
#pragma unroll
        for (int m = 0; m < 4; ++m)
#pragma unroll
            for (int n = 0; n < 2; ++n)
#pragma unroll
                for (int r = 0; r < 4; ++r)
                    rw[((m << 4) + q4 + r) * 33 + (n << 4) + l15] = acc[m][n][r];
    }
    __syncthreads();
    if (w < 4) {
        float* rw = red + (size_t)w * (64 * 33);
#pragma unroll
        for (int m = 0; m < 4; ++m)
#pragma unroll
            for (int n = 0; n < 2; ++n)
#pragma unroll
                for (int r = 0; r < 4; ++r) {
                    int a = ((m << 4) + q4 + r) * 33 + (n << 4) + l15;
                    rw[a] += acc[m][n][r];
                }
    }
    __syncthreads();
#pragma unroll
    for (int i = 0; i < 4; ++i) {
        int e = tid + i * 512;
        int a = (e >> 5) * 33 + (e & 31);
        out4[i] = red[a] + red[64 * 33 + a] + red[2 * 64 * 33 + a] + red[3 * 64 * 33 + a];
    }
}

__global__ __launch_bounds__(NTHREADS, 1) void gru_persistent(
    const float* __restrict__ inputs, const float* __restrict__ state,
    const float* __restrict__ Wxz, const float* __restrict__ Whz, const float* __restrict__ bz,
    const float* __restrict__ Wxr, const float* __restrict__ Whr, const float* __restrict__ br,
    const float* __restrict__ Wxh, const float* __restrict__ Whh, const float* __restrict__ bh,
    const float* __restrict__ Whq, const float* __restrict__ bhq,
    float* __restrict__ out, char* __restrict__ ws) {

    unsigned* bar = (unsigned*)(ws + OFF_BAR);
    __bf16* WxzT = (__bf16*)(ws + OFF_WXZT);
    __bf16* WxrT = (__bf16*)(ws + OFF_WXRT);
    __bf16* WxhT = (__bf16*)(ws + OFF_WXHT);
    __bf16* WhzT = (__bf16*)(ws + OFF_WHZT);
    __bf16* WhrT = (__bf16*)(ws + OFF_WHRT);
    __bf16* WhhT = (__bf16*)(ws + OFF_WHHT);
    __bf16* WhqT = (__bf16*)(ws + OFF_WHQT);
    __bf16* Xbf  = (__bf16*)(ws + OFF_XBF);   // 2 x (64 x 1024)
    __bf16* Hbf  = (__bf16*)(ws + OFF_HBF);   // 2 x (64 x 2048)
    __bf16* RHbf = (__bf16*)(ws + OFF_RHBF);  // 64 x 2048

    __shared__ float red[4 * 64 * 33];        // 33 KB reduction scratch

    const int b   = (int)blockIdx.x;
    const int tid = (int)threadIdx.x;
    const int colbase = (b & 63) * 32;
    unsigned bar_target = 0;

    // ---------------- prologue: weight cvt+transpose, X0/H0 cvt -------------
    transpose_cvt(Wxz, WxzT, I_, 11);
    transpose_cvt(Wxr, WxrT, I_, 11);
    transpose_cvt(Wxh, WxhT, I_, 11);
    transpose_cvt(Whz, WhzT, H_, 11);
    transpose_cvt(Whr, WhrT, H_, 11);
    transpose_cvt(Whh, WhhT, H_, 11);
    transpose_cvt(Whq, WhqT, H_, 10);
    for (int e = b * NTHREADS + tid; e < B_ * I_; e += GSTRIDE)
        Xbf[e] = (__bf16)inputs[e];
    for (int e = b * NTHREADS + tid; e < B_ * H_; e += GSTRIDE)
        Hbf[e] = (__bf16)state[e];

    // register-resident H (f32) and Z for the 32 columns this block owns
    float hreg[4] = {0.f, 0.f, 0.f, 0.f};
    float zreg[4] = {0.f, 0.f, 0.f, 0.f};
    if (b < 64) {
#pragma unroll
        for (int i = 0; i < 4; ++i) {
            int e = tid + i * 512;
            hreg[i] = state[(size_t)(e >> 5) * H_ + colbase + (e & 31)];
        }
    }
    grid_sync(bar, bar_target);

    // ---------------- main recurrence --------------------------------------
    for (int t = 0; t < T_; ++t) {
        const int cur = t & 1, nxt = cur ^ 1;
        const __bf16* Xc = Xbf + (size_t)cur * B_ * I_;
        const __bf16* Hc = Hbf + (size_t)cur * B_ * H_;
        float out4[4];

        // ---- phase A: Z (blocks 0..63) / R,RH (blocks 64..127) ----
        if (b < 64) {
            gemm_block(Xc, I_, 32, WxzT, I_, Hc, H_, 64, WhzT, H_, colbase, red, out4);
#pragma unroll
            for (int i = 0; i < 4; ++i) {
                int e = tid + i * 512;
                zreg[i] = fsigmoid(out4[i] + bz[colbase + (e & 31)]);
            }
        } else {
            gemm_block(Xc, I_, 32, WxrT, I_, Hc, H_, 64, WhrT, H_, colbase, red, out4);
#pragma unroll
            for (int i = 0; i < 4; ++i) {
                int e = tid + i * 512;
                int row = e >> 5, col = colbase + (e & 31);
                float rv = fsigmoid(out4[i] + br[col]);
                RHbf[(size_t)row * H_ + col] = (__bf16)(rv * (float)Hc[(size_t)row * H_ + col]);
            }
        }
        grid_sync(bar, bar_target);

        // ---- phase B: H~/H_new | Y_{t-1} | X_{t+1} conversion ----
        if (b < 64) {
            gemm_block(Xc, I_, 32, WxhT, I_, RHbf, H_, 64, WhhT, H_, colbase, red, out4);
            __bf16* Hn = Hbf + (size_t)nxt * B_ * H_;
#pragma unroll
            for (int i = 0; i < 4; ++i) {
                int e = tid + i * 512;
                int row = e >> 5, col = colbase + (e & 31);
                float ht = ftanh(out4[i] + bh[col]);
                float hn = zreg[i] * hreg[i] + (1.0f - zreg[i]) * ht;
                hreg[i] = hn;
                Hn[(size_t)row * H_ + col] = (__bf16)hn;
                if (t == T_ - 1)
                    out[(size_t)T_ * B_ * I_ + (size_t)row * H_ + col] = hn;  // H_final
            }
        } else if (b < 96) {
            if (t > 0) {
                int cb = (b - 64) * 32;
                gemm_block(Hc, H_, 64, WhqT, H_, Hc, H_, 0, WhqT, H_, cb, red, out4);
#pragma unroll
                for (int i = 0; i < 4; ++i) {
                    int e = tid + i * 512;
                    int row = e >> 5, c = e & 31;
                    out[((size_t)(t - 1) * B_ + row) * I_ + cb + c] = out4[i] + bhq[cb + c];
                }
            }
        } else {
            if (t + 1 < T_) {
                const float* src = inputs + (size_t)(t + 1) * B_ * I_;
                __bf16* dst = Xbf + (size_t)nxt * B_ * I_;
                int base = (b - 96) * 2048;
#pragma unroll
                for (int i = 0; i < 4; ++i) {
                    int e = base + i * 512 + tid;
                    dst[e] = (__bf16)src[e];
                }
            }
        }
        grid_sync(bar, bar_target);
    }

    // ---------------- epilogue: Y_{T-1} ------------------------------------
    if (b < 32) {
        const __bf16* Hc = Hbf + (size_t)(T_ & 1) * B_ * H_;  // = Hbf[0]
        int cb = b * 32;
        float out4[4];
        gemm_block(Hc, H_, 64, WhqT, H_, Hc, H_, 0, WhqT, H_, cb, red, out4);
#pragma unroll
        for (int i = 0; i < 4; ++i) {
            int e = tid + i * 512;
            int row = e >> 5, c = e & 31;
            out[((size_t)(T_ - 1) * B_ + row) * I_ + cb + c] = out4[i] + bhq[cb + c];
        }
    }
}

extern "C" void kernel_launch(void* const* d_in, const int* in_sizes, int n_in,
                              void* d_out, int out_size, void* d_ws, size_t ws_size,
                              hipStream_t stream) {
    if (ws_size < WS_NEEDED) return;  // ~43 MB scratch required

    const float* inputs = (const float*)d_in[0];
    const float* state  = (const float*)d_in[1];
    const float* Wxz    = (const float*)d_in[2];
    const float* Whz    = (const float*)d_in[3];
    const float* bz     = (const float*)d_in[4];
    const float* Wxr    = (const float*)d_in[5];
    const float* Whr    = (const float*)d_in[6];
    const float* br     = (const float*)d_in[7];
    const float* Wxh    = (const float*)d_in[8];
    const float* Whh    = (const float*)d_in[9];
    const float* bh     = (const float*)d_in[10];
    const float* Whq    = (const float*)d_in[11];
    const float* bhq    = (const float*)d_in[12];

    hipMemsetAsync(d_ws, 0, 256, stream);  // barrier counter
    gru_persistent<<<NB, NTHREADS, 0, stream>>>(
        inputs, state, Wxz, Whz, bz, Wxr, Whr, br, Wxh, Whh, bh, Whq, bhq,
        (float*)d_out, (char*)d_ws);
}

// Round 2
// 21640.367 us; speedup vs baseline: 2.9791x; 2.9791x over previous
//
#include <hip/hip_runtime.h>
#include <cstdint>
#include <cstddef>

// ---------------------------------------------------------------------------
// GRU persistent kernel, round 2: fence-free cross-XCD communication.
//   - communicated buffers written with relaxed agent atomics (sc1
//     write-through, no L2 dirty lines -> no buffer_wbl2 anywhere)
//   - one acquire (buffer_inv) per block per barrier, relaxed polling
//   - 8-way distributed barrier arrival counters
//   - 3-deep software-pipelined GEMM K-loop, compile-time X/H segment split
// ---------------------------------------------------------------------------

#define T_ 512
#define B_ 64
#define I_ 1024
#define H_ 2048
#define NB 128
#define NTHREADS 512
#define GSTRIDE (NB * NTHREADS)

typedef __attribute__((ext_vector_type(8))) __bf16 bf16x8;
typedef __attribute__((ext_vector_type(4))) __bf16 bf16x4;
typedef __attribute__((ext_vector_type(4))) float f32x4;

// ---- workspace layout (bytes) ----
static constexpr size_t OFF_BAR  = 0;                      // 8 counters x 64B
static constexpr size_t OFF_WXZT = 1024;
static constexpr size_t SZ_WXT   = (size_t)H_ * I_ * 2;    // 4 MiB
static constexpr size_t SZ_WHT   = (size_t)H_ * H_ * 2;    // 8 MiB
static constexpr size_t OFF_WXRT = OFF_WXZT + SZ_WXT;
static constexpr size_t OFF_WXHT = OFF_WXRT + SZ_WXT;
static constexpr size_t OFF_WHZT = OFF_WXHT + SZ_WXT;
static constexpr size_t OFF_WHRT = OFF_WHZT + SZ_WHT;
static constexpr size_t OFF_WHHT = OFF_WHRT + SZ_WHT;
static constexpr size_t OFF_WHQT = OFF_WHHT + SZ_WHT;      // N=1024,K=2048
static constexpr size_t OFF_XBF  = OFF_WHQT + SZ_WXT;
static constexpr size_t OFF_HBF  = OFF_XBF + (size_t)2 * B_ * I_ * 2;
static constexpr size_t OFF_RHBF = OFF_HBF + (size_t)2 * B_ * H_ * 2;
static constexpr size_t WS_NEEDED = OFF_RHBF + (size_t)B_ * H_ * 2;

__device__ __forceinline__ float fsigmoid(float x) { return 1.0f / (1.0f + __expf(-x)); }
__device__ __forceinline__ float ftanh(float x)    { return 2.0f / (1.0f + __expf(-2.0f * x)) - 1.0f; }

// ---- coherent (sc1 write-through) stores for cross-block data ----
__device__ __forceinline__ void cstore8(void* p, unsigned long long v) {
    __hip_atomic_store((unsigned long long*)p, v, __ATOMIC_RELAXED, __HIP_MEMORY_SCOPE_AGENT);
}
__device__ __forceinline__ unsigned long long pack4bf(float a, float b, float c, float d) {
    union { unsigned short s[4]; unsigned long long u; } x;
    union { __bf16 b; unsigned short s; } t;
    t.b = (__bf16)a; x.s[0] = t.s;
    t.b = (__bf16)b; x.s[1] = t.s;
    t.b = (__bf16)c; x.s[2] = t.s;
    t.b = (__bf16)d; x.s[3] = t.s;
    return x.u;
}

// ---- fence-free grid barrier ----
// Arrival: relaxed fetch_add on one of 8 cacheline-spread counters (stores
// already drained by __syncthreads' pre-barrier s_waitcnt vmcnt(0); they are
// sc1 write-through so completion == global visibility).
// Poll: relaxed loads (no cache maintenance). After success: ONE acquire load
// -> single buffer_inv so subsequent normal loads see fresh data.
__device__ __forceinline__ void grid_sync(unsigned* bars, unsigned& target) {
    __syncthreads();
    target += (unsigned)NB;
    if (threadIdx.x == 0) {
        __hip_atomic_fetch_add(&bars[(blockIdx.x & 7) * 16], 1u,
                               __ATOMIC_RELAXED, __HIP_MEMORY_SCOPE_AGENT);
        for (;;) {
            unsigned sum = 0;
#pragma unroll
            for (int g = 0; g < 8; ++g)
                sum += __hip_atomic_load(&bars[g * 16],
                                         __ATOMIC_RELAXED, __HIP_MEMORY_SCOPE_AGENT);
            if (sum >= target) break;
            __builtin_amdgcn_s_sleep(2);
        }
        (void)__hip_atomic_load(&bars[0], __ATOMIC_ACQUIRE, __HIP_MEMORY_SCOPE_AGENT);
    }
    __syncthreads();
    asm volatile("" ::: "memory");
}

// prologue-only barrier: full fence (weight transpose uses normal cached
// stores; one-time wbl2 makes them globally visible)
__device__ __forceinline__ void grid_sync_full(unsigned* bars, unsigned& target) {
    __syncthreads();
    __threadfence();
    target += (unsigned)NB;
    if (threadIdx.x == 0) {
        __hip_atomic_fetch_add(&bars[(blockIdx.x & 7) * 16], 1u,
                               __ATOMIC_RELAXED, __HIP_MEMORY_SCOPE_AGENT);
        for (;;) {
            unsigned sum = 0;
#pragma unroll
            for (int g = 0; g < 8; ++g)
                sum += __hip_atomic_load(&bars[g * 16],
                                         __ATOMIC_RELAXED, __HIP_MEMORY_SCOPE_AGENT);
            if (sum >= target) break;
            __builtin_amdgcn_s_sleep(2);
        }
        (void)__hip_atomic_load(&bars[0], __ATOMIC_ACQUIRE, __HIP_MEMORY_SCOPE_AGENT);
    }
    __syncthreads();
    asm volatile("" ::: "memory");
}

// f32 (K x N row-major) -> bf16 transposed (N x K row-major), normal stores
__device__ __forceinline__ void transpose_cvt(const float* __restrict__ src,
                                              __bf16* __restrict__ dst,
                                              int K, int lgN) {
    const int N = 1 << lgN;
    const int total = K << lgN;
    for (int idx = (int)(blockIdx.x * blockDim.x + threadIdx.x); idx < total; idx += GSTRIDE) {
        int k = idx >> lgN;
        int n = idx & (N - 1);
        dst[(size_t)n * K + k] = (__bf16)src[idx];
    }
}

// ---------------------------------------------------------------------------
// Pipelined block GEMM. Tile = 64 rows x 32 cols at column base `colbase`.
// K split 8 ways across waves; segment schedule is compile-time: for wave w,
// iterations [0,IX) are X-part segments (K-stride 1024), [IX,IX+IH) are
// H-part segments (K-stride 2048).  IX*8*32 == Kx, IH*8*32 == Kh.
// 3-deep software pipeline: loads for segment i+3 issue before MFMAs of i.
// Output: out4[j] = C[row = tid>>3][col = colbase + ((tid&7)*4) + j].
// ---------------------------------------------------------------------------
template<int IX, int IH>
__device__ __forceinline__ void gemm_pipe(
    const __bf16* __restrict__ Ax, const __bf16* __restrict__ Bxt,
    const __bf16* __restrict__ Ah, const __bf16* __restrict__ Bht,
    int colbase, float* __restrict__ red, float out4[4])
{
    constexpr int ITER = IX + IH;
    const int tid  = (int)threadIdx.x;
    const int lane = tid & 63;
    const int w    = tid >> 6;
    const int l15  = lane & 15;
    const int q8   = (lane >> 4) << 3;   // k offset of this quad
    const int q4   = (lane >> 4) << 2;   // row offset (C/D layout)

    f32x4 acc[4][2];
#pragma unroll
    for (int m = 0; m < 4; ++m) {
        acc[m][0] = f32x4{0.f, 0.f, 0.f, 0.f};
        acc[m][1] = f32x4{0.f, 0.f, 0.f, 0.f};
    }

    bf16x8 pa[3][4];
    bf16x8 pb[3][2];

    auto lseg = [&](int i, int s) {
        const bool isx = (i < IX);
        const __bf16* A  = isx ? Ax : Ah;
        const __bf16* Bt = isx ? Bxt : Bht;
        const int ks = isx ? I_ : H_;   // K-dim == A row stride == Bt row len
        const int kb = (isx ? ((w + (i << 3)) << 5)
                            : ((w + ((i - IX) << 3)) << 5)) + q8;
        pb[s][0] = *(const bf16x8*)(Bt + (size_t)(colbase + l15) * ks + kb);
        pb[s][1] = *(const bf16x8*)(Bt + (size_t)(colbase + 16 + l15) * ks + kb);
#pragma unroll
        for (int m = 0; m < 4; ++m)
            pa[s][m] = *(const bf16x8*)(A + (size_t)((m << 4) + l15) * ks + kb);
    };

    lseg(0, 0);
    if constexpr (ITER > 1) lseg(1, 1);
    if constexpr (ITER > 2) lseg(2, 2);
#pragma unroll
    for (int i = 0; i < ITER; ++i) {
        const int s = i % 3;
#pragma unroll
        for (int m = 0; m < 4; ++m) {
            acc[m][0] = __builtin_amdgcn_mfma_f32_16x16x32_bf16(pa[s][m], pb[s][0], acc[m][0], 0, 0, 0);
            acc[m][1] = __builtin_amdgcn_mfma_f32_16x16x32_bf16(pa[s][m], pb[s][1], acc[m][1], 0, 0, 0);
        }
        if (i + 3 < ITER) lseg(i + 3, s);
    }

    // cross-wave reduction through LDS (pad 36 -> aligned float4 gather)
    if (w >= 4) {
        float* rw = red + (size_t)(w - 4) * (64 * 36);
#pragma unroll
        for (int m = 0; m < 4; ++m)
#pragma unroll
            for (int n = 0; n < 2; ++n)
#pragma unroll
                for (int r = 0; r < 4; ++r)
                    rw[((m << 4) + q4 + r) * 36 + (n << 4) + l15] = acc[m][n][r];
    }
    __syncthreads();
    if (w < 4) {
        float* rw = red + (size_t)w * (64 * 36);
#pragma unroll
        for (int m = 0; m < 4; ++m)
#pragma unroll
            for (int n = 0; n < 2; ++n)
#pragma unroll
                for (int r = 0; r < 4; ++r) {
                    int a = ((m << 4) + q4 + r) * 36 + (n << 4) + l15;
                    rw[a] += acc[m][n][r];
                }
    }
    __syncthreads();
    {
        const int gr = tid >> 3;
        const int gc = (tid & 7) << 2;
        const int a = gr * 36 + gc;
        f32x4 s0 = *(const f32x4*)(red + a);
        f32x4 s1 = *(const f32x4*)(red + 64 * 36 + a);
        f32x4 s2 = *(const f32x4*)(red + 2 * 64 * 36 + a);
        f32x4 s3 = *(const f32x4*)(red + 3 * 64 * 36 + a);
        f32x4 s = s0 + s1 + s2 + s3;
#pragma unroll
        for (int j = 0; j < 4; ++j) out4[j] = s[j];
    }
}

__global__ __launch_bounds__(NTHREADS, 1) void gru_persistent(
    const float* __restrict__ inputs, const float* __restrict__ state,
    const float* __restrict__ Wxz, const float* __restrict__ Whz, const float* __restrict__ bz,
    const float* __restrict__ Wxr, const float* __restrict__ Whr, const float* __restrict__ br,
    const float* __restrict__ Wxh, const float* __restrict__ Whh, const float* __restrict__ bh,
    const float* __restrict__ Whq, const float* __restrict__ bhq,
    float* __restrict__ out, char* __restrict__ ws) {

    unsigned* bars = (unsigned*)(ws + OFF_BAR);
    __bf16* WxzT = (__bf16*)(ws + OFF_WXZT);
    __bf16* WxrT = (__bf16*)(ws + OFF_WXRT);
    __bf16* WxhT = (__bf16*)(ws + OFF_WXHT);
    __bf16* WhzT = (__bf16*)(ws + OFF_WHZT);
    __bf16* WhrT = (__bf16*)(ws + OFF_WHRT);
    __bf16* WhhT = (__bf16*)(ws + OFF_WHHT);
    __bf16* WhqT = (__bf16*)(ws + OFF_WHQT);
    __bf16* Xbf  = (__bf16*)(ws + OFF_XBF);   // 2 x (64 x 1024)
    __bf16* Hbf  = (__bf16*)(ws + OFF_HBF);   // 2 x (64 x 2048)
    __bf16* RHbf = (__bf16*)(ws + OFF_RHBF);  // 64 x 2048

    __shared__ float red[4 * 64 * 36];        // 36 KB reduction scratch

    const int b   = (int)blockIdx.x;
    const int tid = (int)threadIdx.x;
    const int colbase = (b & 63) * 32;
    const int gr = tid >> 3;                  // output row this thread owns
    const int gc = (tid & 7) << 2;            // output col (4 consecutive)
    unsigned bar_target = 0;

    // ---------------- prologue ---------------------------------------------
    transpose_cvt(Wxz, WxzT, I_, 11);
    transpose_cvt(Wxr, WxrT, I_, 11);
    transpose_cvt(Wxh, WxhT, I_, 11);
    transpose_cvt(Whz, WhzT, H_, 11);
    transpose_cvt(Whr, WhrT, H_, 11);
    transpose_cvt(Whh, WhhT, H_, 11);
    transpose_cvt(Whq, WhqT, H_, 10);
    {
        int q = b * NTHREADS + tid;           // quad index
        if (q < B_ * I_ / 4) {
            f32x4 v = *(const f32x4*)(inputs + (size_t)q * 4);
            cstore8(Xbf + (size_t)q * 4, pack4bf(v[0], v[1], v[2], v[3]));
        }
        if (q < B_ * H_ / 4) {
            f32x4 v = *(const f32x4*)(state + (size_t)q * 4);
            cstore8(Hbf + (size_t)q * 4, pack4bf(v[0], v[1], v[2], v[3]));
        }
    }

    // register-resident H (f32) and Z for the 4 cols x row this thread owns
    float hreg[4] = {0.f, 0.f, 0.f, 0.f};
    float zreg[4] = {0.f, 0.f, 0.f, 0.f};
    if (b < 64) {
        f32x4 v = *(const f32x4*)(state + (size_t)gr * H_ + colbase + gc);
#pragma unroll
        for (int j = 0; j < 4; ++j) hreg[j] = v[j];
    }
    grid_sync_full(bars, bar_target);

    // ---------------- main recurrence --------------------------------------
    for (int t = 0; t < T_; ++t) {
        const int cur = t & 1, nxt = cur ^ 1;
        const __bf16* Xc = Xbf + (size_t)cur * B_ * I_;
        const __bf16* Hc = Hbf + (size_t)cur * B_ * H_;
        float out4[4];

        // ---- phase A: Z (blocks 0..63) / R,RH (blocks 64..127) ----
        if (b < 64) {
            gemm_pipe<4, 8>(Xc, WxzT, Hc, WhzT, colbase, red, out4);
            f32x4 bv = *(const f32x4*)(bz + colbase + gc);
#pragma unroll
            for (int j = 0; j < 4; ++j) zreg[j] = fsigmoid(out4[j] + bv[j]);
        } else {
            gemm_pipe<4, 8>(Xc, WxrT, Hc, WhrT, colbase, red, out4);
            f32x4 bv = *(const f32x4*)(br + colbase + gc);
            bf16x4 h4 = *(const bf16x4*)(Hc + (size_t)gr * H_ + colbase + gc);
            float rh[4];
#pragma unroll
            for (int j = 0; j < 4; ++j)
                rh[j] = fsigmoid(out4[j] + bv[j]) * (float)h4[j];
            cstore8(RHbf + (size_t)gr * H_ + colbase + gc,
                    pack4bf(rh[0], rh[1], rh[2], rh[3]));
        }
        grid_sync(bars, bar_target);

        // ---- phase B: H~/H_new | Y_{t-1} | X_{t+1} conversion ----
        if (b < 64) {
            gemm_pipe<4, 8>(Xc, WxhT, RHbf, WhhT, colbase, red, out4);
            f32x4 bv = *(const f32x4*)(bh + colbase + gc);
            float hn[4];
#pragma unroll
            for (int j = 0; j < 4; ++j) {
                float ht = ftanh(out4[j] + bv[j]);
                hn[j] = zreg[j] * hreg[j] + (1.0f - zreg[j]) * ht;
                hreg[j] = hn[j];
            }
            cstore8(Hbf + (size_t)nxt * B_ * H_ + (size_t)gr * H_ + colbase + gc,
                    pack4bf(hn[0], hn[1], hn[2], hn[3]));
            if (t == T_ - 1) {
                f32x4 v; v[0] = hn[0]; v[1] = hn[1]; v[2] = hn[2]; v[3] = hn[3];
                *(f32x4*)(out + (size_t)T_ * B_ * I_ + (size_t)gr * H_ + colbase + gc) = v;
            }
        } else if (b < 96) {
            if (t > 0) {
                const int cb = (b - 64) * 32;
                gemm_pipe<0, 8>(nullptr, nullptr, Hc, WhqT, cb, red, out4);
                f32x4 bv = *(const f32x4*)(bhq + cb + gc);
                f32x4 v;
#pragma unroll
                for (int j = 0; j < 4; ++j) v[j] = out4[j] + bv[j];
                *(f32x4*)(out + ((size_t)(t - 1) * B_ + gr) * I_ + cb + gc) = v;
            }
        } else {
            if (t + 1 < T_) {
                const int idx = ((b - 96) * NTHREADS + tid) * 4;
                f32x4 v = *(const f32x4*)(inputs + (size_t)(t + 1) * B_ * I_ + idx);
                cstore8(Xbf + (size_t)nxt * B_ * I_ + idx,
                        pack4bf(v[0], v[1], v[2], v[3]));
            }
        }
        grid_sync(bars, bar_target);
    }

    // ---------------- epilogue: Y_{T-1} ------------------------------------
    if (b < 32) {
        const __bf16* Hc = Hbf;   // slot (T_ & 1) == 0
        const int cb = b * 32;
        float out4[4];
        gemm_pipe<0, 8>(nullptr, nullptr, Hc, WhqT, cb, red, out4);
        f32x4 bv = *(const f32x4*)(bhq + cb + gc);
        f32x4 v;
#pragma unroll
        for (int j = 0; j < 4; ++j) v[j] = out4[j] + bv[j];
        *(f32x4*)(out + ((size_t)(T_ - 1) * B_ + gr) * I_ + cb + gc) = v;
    }
}

extern "C" void kernel_launch(void* const* d_in, const int* in_sizes, int n_in,
                              void* d_out, int out_size, void* d_ws, size_t ws_size,
                              hipStream_t stream) {
    if (ws_size < WS_NEEDED) return;  // ~41.5 MB scratch required

    const float* inputs = (const float*)d_in[0];
    const float* state  = (const float*)d_in[1];
    const float* Wxz    = (const float*)d_in[2];
    const float* Whz    = (const float*)d_in[3];
    const float* bz     = (const float*)d_in[4];
    const float* Wxr    = (const float*)d_in[5];
    const float* Whr    = (const float*)d_in[6];
    const float* br     = (const float*)d_in[7];
    const float* Wxh    = (const float*)d_in[8];
    const float* Whh    = (const float*)d_in[9];
    const float* bh     = (const float*)d_in[10];
    const float* Whq    = (const float*)d_in[11];
    const float* bhq    = (const float*)d_in[12];

    hipMemsetAsync(d_ws, 0, 1024, stream);  // barrier counters
    gru_persistent<<<NB, NTHREADS, 0, stream>>>(
        inputs, state, Wxz, Whz, bz, Wxr, Whr, br, Wxh, Whh, bh, Whq, bhq,
        (float*)d_out, (char*)d_ws);
}